// Round 11
// baseline (168.341 us; speedup 1.0000x reference)
//
#include <hip/hip_runtime.h>
#include <stdint.h>
#include <math.h>

#define N 8192
#define CAP 8
#define OVF_MAX 4096

// async global->LDS DMA, 16 B per lane (per-lane source, uniform dest base)
__device__ __forceinline__ void gl_lds16(const void* g, void* l) {
    __builtin_amdgcn_global_load_lds(
        (const __attribute__((address_space(1))) void*)g,
        (__attribute__((address_space(3))) void*)l, 16, 0, 0);
}

// ================= Sort stage (bitonic, exact argsort) =================
// key = (~monotone(score) << 32) | index; ascending sort == stable argsort
// of -scores. Network split: local k<=2048 (s1), k=4096 (s2), k=8192 (s3).

__global__ __launch_bounds__(1024) void k_sort1(const float* __restrict__ scores,
                                                uint64_t* __restrict__ keys,
                                                char* __restrict__ hdr,
                                                uint32_t* __restrict__ ovfc) {
    __shared__ uint64_t sk[2048];
    int b = blockIdx.x, t = threadIdx.x;
    int base = b * 2048;
    // zero the per-row packed-entry counters in the chunk headers.
    {
        int r0 = base + t, r1 = base + t + 1024;
        *((uint32_t*)(hdr + (size_t)(r0 >> 6) * 1024 + 512) + (r0 & 63)) = 0;
        *((uint32_t*)(hdr + (size_t)(r1 >> 6) * 1024 + 512) + (r1 & 63)) = 0;
    }
    if (b == 0 && t == 0) *ovfc = 0;
    for (int e = 0; e < 2; ++e) {
        int li = t + e * 1024;
        int i = base + li;
        uint32_t sb = __float_as_uint(scores[i]);
        sb = (sb & 0x80000000u) ? ~sb : (sb | 0x80000000u);
        sk[li] = ((uint64_t)(~sb) << 32) | (uint32_t)i;
    }
    __syncthreads();
    for (int k = 2; k <= 2048; k <<= 1) {
        for (int j = k >> 1; j > 0; j >>= 1) {
            for (int e = 0; e < 2; ++e) {
                int li = t + e * 1024;
                int lixj = li ^ j;
                if (lixj > li) {
                    int gi = base + li;
                    bool up = ((gi & k) == 0);
                    uint64_t a = sk[li], c = sk[lixj];
                    if ((a > c) == up) { sk[li] = c; sk[lixj] = a; }
                }
            }
            __syncthreads();
        }
    }
    for (int e = 0; e < 2; ++e) { int li = t + e * 1024; keys[base + li] = sk[li]; }
}

// k=4096: cross pass j=2048 read from global (element-wise), then local j<=1024.
__global__ __launch_bounds__(1024) void k_sort2(const uint64_t* __restrict__ keys,
                                                uint64_t* __restrict__ keys2) {
    __shared__ uint64_t sk[2048];
    int b = blockIdx.x, t = threadIdx.x;
    int base = b * 2048;
    for (int e = 0; e < 2; ++e) {
        int li = t + e * 1024;
        int i = base + li;
        uint64_t a = keys[i], c = keys[i ^ 2048];
        bool up = ((i & 4096) == 0);
        bool lowpos = ((i & 2048) == 0);
        uint64_t mn = a < c ? a : c, mx = a < c ? c : a;
        sk[li] = (up == lowpos) ? mn : mx;
    }
    __syncthreads();
    for (int j = 1024; j > 0; j >>= 1) {
        for (int e = 0; e < 2; ++e) {
            int li = t + e * 1024;
            int lixj = li ^ j;
            if (lixj > li) {
                int gi = base + li;
                bool up = ((gi & 4096) == 0);
                uint64_t a = sk[li], c = sk[lixj];
                if ((a > c) == up) { sk[li] = c; sk[lixj] = a; }
            }
        }
        __syncthreads();
    }
    for (int e = 0; e < 2; ++e) { int li = t + e * 1024; keys2[base + li] = sk[li]; }
}

// k=8192 (up=true everywhere): cross passes j=4096,2048 from global, local
// j<=1024, then fused gather of boxes/scores into sorted order.
__global__ __launch_bounds__(1024) void k_sort3(const uint64_t* __restrict__ keys2,
                                                const float4* __restrict__ boxes,
                                                const float* __restrict__ scores,
                                                float4* __restrict__ bs,
                                                float* __restrict__ ss) {
    __shared__ uint64_t sk[2048];
    int b = blockIdx.x, t = threadIdx.x;
    int base = b * 2048;
    for (int e = 0; e < 2; ++e) {
        int li = t + e * 1024;
        int i = base + li;
        uint64_t a0 = keys2[i], a1 = keys2[i ^ 4096];
        bool low0 = ((i & 4096) == 0);
        uint64_t v = low0 ? (a0 < a1 ? a0 : a1) : (a0 < a1 ? a1 : a0);
        int q = i ^ 2048;
        uint64_t b0 = keys2[q], b1 = keys2[q ^ 4096];
        bool lowq = ((q & 4096) == 0);
        uint64_t vq = lowq ? (b0 < b1 ? b0 : b1) : (b0 < b1 ? b1 : b0);
        bool low2 = ((i & 2048) == 0);
        sk[li] = low2 ? (v < vq ? v : vq) : (v < vq ? vq : v);
    }
    __syncthreads();
    for (int j = 1024; j > 0; j >>= 1) {
        for (int e = 0; e < 2; ++e) {
            int li = t + e * 1024;
            int lixj = li ^ j;
            if (lixj > li) {
                uint64_t a = sk[li], c = sk[lixj];
                if (a > c) { sk[li] = c; sk[lixj] = a; }   // up = true
            }
        }
        __syncthreads();
    }
    for (int e = 0; e < 2; ++e) {
        int li = t + e * 1024;
        int gi = base + li;
        uint32_t idx = (uint32_t)sk[li];
        bs[gi] = boxes[idx];
        ss[gi] = scores[idx];
    }
}

// ---------------- Suppression bitmask -> sparse packed ----------------
// One wave per upper-triangle (R, word) tile; 8256 tiles = 2064 blocks x 4
// waves, perfectly balanced, zero barriers. Per chunk-header: diag word +
// entry count; nonzero off-diagonal words appended to transposed pkT[e*N+row];
// entries beyond CAP go to a tiny global overflow list.
__global__ __launch_bounds__(256) void k_mask(const float4* __restrict__ bs,
                                              ulonglong2* __restrict__ pkT,
                                              char* __restrict__ hdr,
                                              ulonglong2* __restrict__ ovf,
                                              uint32_t* __restrict__ ovfc) {
    __shared__ float4 rb[4][64];
    __shared__ float  ra[4][64];
    int t = threadIdx.x;
    int lane = t & 63;
    int wv = t >> 6;
    int tile = blockIdx.x * 4 + wv;          // 0..8255

    // decode tile -> (R, word): off(R) = 128R - R(R-1)/2, word >= R
    int R = (int)((257.0 - sqrt(66049.0 - 8.0 * (double)tile)) * 0.5);
    while (128 * (R + 1) - ((R + 1) * R) / 2 <= tile) ++R;   // safety correction
    while (128 * R - (R * (R - 1)) / 2 > tile) --R;
    int word = R + tile - (128 * R - (R * (R - 1)) / 2);

    {   // stage this wave's 64 row boxes (wave-private LDS, no barrier needed)
        float4 b = bs[R * 64 + lane];
        rb[wv][lane] = b;
        ra[wv][lane] = ((b.z - b.x) + 1.0f) * ((b.w - b.y) + 1.0f);
    }
    int col = word * 64 + lane;
    float4 cb = bs[col];
    float ca = ((cb.z - cb.x) + 1.0f) * ((cb.w - cb.y) + 1.0f);

    uint64_t* dg = (uint64_t*)(hdr + (size_t)R * 1024);
    uint32_t* cp = (uint32_t*)(hdr + (size_t)R * 1024 + 512);

    for (int r = 0; r < 64; ++r) {
        int row = R * 64 + r;
        float4 rbv = rb[wv][r];
        float ix1 = fmaxf(rbv.x, cb.x);
        float iy1 = fmaxf(rbv.y, cb.y);
        float ix2 = fminf(rbv.z, cb.z);
        float iy2 = fminf(rbv.w, cb.w);
        float iw = fmaxf((ix2 - ix1) + 1.0f, 0.0f);
        float ih = fmaxf((iy2 - iy1) + 1.0f, 0.0f);
        float inter = iw * ih;
        float uni = (ra[wv][r] + ca) - inter;   // matches ref order
        float iou = inter / uni;                // IEEE div, matches numpy ref
        bool pred = (iou > 0.5f) && (col > row);
        uint64_t bal = __ballot(pred);
        if (lane == 0) {
            if (word == R) {
                dg[r] = bal;                     // intra-chunk (diag) word
            } else if (bal) {
                uint32_t pos = atomicAdd(&cp[r], 1u);
                if (pos < CAP) {
                    ulonglong2 v;
                    v.x = bal; v.y = (unsigned long long)word;
                    pkT[(size_t)pos * N + row] = v;
                } else {
                    uint32_t op = atomicAdd(ovfc, 1u);
                    if (op < OVF_MAX) {
                        ulonglong2 v;
                        v.x = bal;
                        v.y = (unsigned long long)word |
                              ((unsigned long long)row << 32);
                        ovf[op] = v;
                    }
                }
            }
        }
    }
}

// ---------------- Sparse single-wave greedy scan (depth-3 counted DMA) -------
// 64 threads, zero barriers. 4 LDS stage buffers; 9 DMAs/chunk (8 entry rows
// + 1 header with diag|cnt). Counted vmcnt: wait vmcnt(18) leaves the 2
// younger chunks in flight (T4 -- never drain to 0 mid-loop); lead time ~3
// chunks covers the L3/HBM miss latency that depth-1 couldn't (R9/R10).
__global__ __launch_bounds__(64, 1) void k_scan(const ulonglong2* __restrict__ pkT,
                                                const char* __restrict__ hdr,
                                                const ulonglong2* __restrict__ ovf,
                                                const uint32_t* __restrict__ ovfc,
                                                uint64_t* __restrict__ keepw) {
    __shared__ uint64_t sh_remv[128];
    __shared__ __align__(16) char stage[4][9216];   // [8KB entries | 1KB hdr]
    const int lane = threadIdx.x;
    sh_remv[lane] = 0;
    sh_remv[64 + lane] = 0;
    const int novf = min((int)*ovfc, OVF_MAX);

    // prologue: DMA chunks 0,1,2
#pragma unroll
    for (int pc = 0; pc < 3; ++pc) {
        char* db = stage[pc];
#pragma unroll
        for (int e = 0; e < CAP; ++e)
            gl_lds16(pkT + (size_t)e * N + pc * 64 + lane, db + e * 1024);
        gl_lds16(hdr + (size_t)pc * 1024 + lane * 16, db + 8192);
    }

#define W18 asm volatile("s_waitcnt vmcnt(18)" ::: "memory")
#define W9  asm volatile("s_waitcnt vmcnt(9)"  ::: "memory")
#define W0  asm volatile("s_waitcnt vmcnt(0)"  ::: "memory")

#define PROCESS(C_, PAR, WAITOP)                                               \
    {                                                                          \
        const int c_ = (C_);                                                   \
        WAITOP;   /* chunk c_'s 9 DMAs (never among 18 newest) are complete */ \
        const char* sb = stage[PAR];                                           \
        uint64_t d_cur = ((const uint64_t*)(sb + 8192))[lane];                 \
        uint32_t c_cur = ((const uint32_t*)(sb + 8192 + 512))[lane];           \
        if (c_ + 3 < 128) {  /* issue chunk c_+3 into buffer (PAR+3)&3 */      \
            char* db = stage[(PAR + 3) & 3];                                   \
            _Pragma("unroll")                                                  \
            for (int e = 0; e < CAP; ++e)                                      \
                gl_lds16(pkT + (size_t)e * N + (c_ + 3) * 64 + lane,           \
                         db + e * 1024);                                       \
            gl_lds16(hdr + (size_t)(c_ + 3) * 1024 + lane * 16, db + 8192);    \
        }                                                                      \
        ulonglong2 n0 = ((const ulonglong2*)(sb + 0 * 1024))[lane];            \
        ulonglong2 n1 = ((const ulonglong2*)(sb + 1 * 1024))[lane];            \
        ulonglong2 n2 = ((const ulonglong2*)(sb + 2 * 1024))[lane];            \
        ulonglong2 n3 = ((const ulonglong2*)(sb + 3 * 1024))[lane];            \
        ulonglong2 n4 = ((const ulonglong2*)(sb + 4 * 1024))[lane];            \
        ulonglong2 n5 = ((const ulonglong2*)(sb + 5 * 1024))[lane];            \
        ulonglong2 n6 = ((const ulonglong2*)(sb + 6 * 1024))[lane];            \
        ulonglong2 n7 = ((const ulonglong2*)(sb + 7 * 1024))[lane];            \
        /* sparse scalar serial recurrence */                                  \
        uint64_t nzv = __ballot(d_cur != 0);                                   \
        uint32_t nlo = __builtin_amdgcn_readfirstlane((uint32_t)nzv);          \
        uint32_t nhi = __builtin_amdgcn_readfirstlane((uint32_t)(nzv >> 32));  \
        uint64_t nz = ((uint64_t)nhi << 32) | nlo;                             \
        uint32_t mlo = (uint32_t)d_cur, mhi = (uint32_t)(d_cur >> 32);         \
        asm volatile("s_waitcnt lgkmcnt(0)" ::: "memory");                     \
        uint64_t wvv = sh_remv[c_];                                            \
        uint32_t wlo = __builtin_amdgcn_readfirstlane((uint32_t)wvv);          \
        uint32_t whi = __builtin_amdgcn_readfirstlane((uint32_t)(wvv >> 32));  \
        uint64_t w_ = ((uint64_t)whi << 32) | wlo;                             \
        while (nz) {                                                           \
            int i = (int)__builtin_ctzll(nz);                                  \
            nz &= nz - 1;                                                      \
            if (!((w_ >> i) & 1ull)) {                                         \
                uint32_t lo = __builtin_amdgcn_readlane(mlo, i);               \
                uint32_t hi = __builtin_amdgcn_readlane(mhi, i);               \
                w_ |= ((uint64_t)hi << 32) | lo;                               \
            }                                                                  \
        }                                                                      \
        if (lane == 0) sh_remv[c_] = w_;                                       \
        if (!((w_ >> lane) & 1ull)) {  /* kept: scatter future words */        \
            if (0 < (int)c_cur) atomicOr((unsigned long long*)&sh_remv[(int)n0.y], (unsigned long long)n0.x); \
            if (1 < (int)c_cur) atomicOr((unsigned long long*)&sh_remv[(int)n1.y], (unsigned long long)n1.x); \
            if (2 < (int)c_cur) atomicOr((unsigned long long*)&sh_remv[(int)n2.y], (unsigned long long)n2.x); \
            if (3 < (int)c_cur) atomicOr((unsigned long long*)&sh_remv[(int)n3.y], (unsigned long long)n3.x); \
            if (4 < (int)c_cur) atomicOr((unsigned long long*)&sh_remv[(int)n4.y], (unsigned long long)n4.x); \
            if (5 < (int)c_cur) atomicOr((unsigned long long*)&sh_remv[(int)n5.y], (unsigned long long)n5.x); \
            if (6 < (int)c_cur) atomicOr((unsigned long long*)&sh_remv[(int)n6.y], (unsigned long long)n6.x); \
            if (7 < (int)c_cur) atomicOr((unsigned long long*)&sh_remv[(int)n7.y], (unsigned long long)n7.x); \
        }                                                                      \
        uint64_t ovb = __ballot(c_cur > CAP);  /* exact overflow completion */ \
        if (ovb) {                                                             \
            for (int e = lane; e < novf; e += 64) {                            \
                ulonglong2 en = ovf[e];                                        \
                int erow = (int)(en.y >> 32);                                  \
                if ((erow >> 6) == c_ && !((w_ >> (erow & 63)) & 1ull))        \
                    atomicOr((unsigned long long*)&sh_remv[(int)(uint32_t)en.y],\
                             (unsigned long long)en.x);                        \
            }                                                                  \
        }                                                                      \
    }

    for (int cc = 0; cc < 124; cc += 4) {
        PROCESS(cc + 0, 0, W18)
        PROCESS(cc + 1, 1, W18)
        PROCESS(cc + 2, 2, W18)
        PROCESS(cc + 3, 3, W18)
    }
    PROCESS(124, 0, W18)
    PROCESS(125, 1, W18)
    PROCESS(126, 2, W9)
    PROCESS(127, 3, W0)
#undef PROCESS
#undef W18
#undef W9
#undef W0

    // single coalesced keep write-out
    asm volatile("s_waitcnt lgkmcnt(0)" ::: "memory");
    keepw[lane] = ~sh_remv[lane];
    keepw[64 + lane] = ~sh_remv[64 + lane];
}

// ---------------- Masked outputs ----------------
__global__ void k_out(const float4* __restrict__ bs, const float* __restrict__ ss,
                      const uint64_t* __restrict__ keepw, float* __restrict__ out) {
    int i = blockIdx.x * blockDim.x + threadIdx.x;
    uint64_t wv = keepw[i >> 6];
    float m = ((wv >> (i & 63)) & 1ull) ? 1.0f : 0.0f;
    float4 b = bs[i];
    float4 ob;
    ob.x = b.x * m; ob.y = b.y * m; ob.z = b.z * m; ob.w = b.w * m;
    ((float4*)out)[i] = ob;
    out[4 * N + i] = ss[i] * m;
    out[5 * N + i] = m;
}

extern "C" void kernel_launch(void* const* d_in, const int* in_sizes, int n_in,
                              void* d_out, int out_size, void* d_ws, size_t ws_size,
                              hipStream_t stream) {
    const float* boxes  = (const float*)d_in[0];   // 8192 x 4 f32
    const float* scores = (const float*)d_in[1];   // 8192 f32

    char* ws = (char*)d_ws;
    float4*     bs    = (float4*)(ws + 0);          // 131072 B
    float*      ss    = (float*)(ws + 131072);      //  32768 B
    uint64_t*   keepw = (uint64_t*)(ws + 163840);   //   1024 B
    uint32_t*   ovfc  = (uint32_t*)(ws + 164864);   //    512 B (padded)
    ulonglong2* ovf   = (ulonglong2*)(ws + 165376); //  65536 B (4096 x 16)
    char*       hdr   = (char*)(ws + 231424);       // 131072 B (128 x 1KB)
    uint64_t*   keys  = (uint64_t*)(ws + 362496);   //  65536 B
    uint64_t*   keys2 = (uint64_t*)(ws + 428032);   //  65536 B
    ulonglong2* pkT   = (ulonglong2*)(ws + 524288); // 1048576 B (CAP x N x 16)

    k_sort1<<<4, 1024, 0, stream>>>(scores, keys, hdr, ovfc);
    k_sort2<<<4, 1024, 0, stream>>>(keys, keys2);
    k_sort3<<<4, 1024, 0, stream>>>(keys2, (const float4*)boxes, scores, bs, ss);
    k_mask <<<2064, 256, 0, stream>>>(bs, pkT, hdr, ovf, ovfc);
    k_scan <<<1, 64, 0, stream>>>(pkT, hdr, ovf, ovfc, keepw);
    k_out  <<<N / 256, 256, 0, stream>>>(bs, ss, keepw, (float*)d_out);
}

// Round 14
// 149.940 us; speedup vs baseline: 1.1227x; 1.1227x over previous
//
#include <hip/hip_runtime.h>
#include <stdint.h>
#include <math.h>

#define N 8192
#define CAP 8
#define OVF_MAX 4096

// ================= Sort stage (bitonic, exact argsort) =================
// key = (~monotone(score) << 32) | index; ascending sort == stable argsort
// of -scores. Network split: local k<=2048 (s1), k=4096 (s2), k=8192 (s3).

__global__ __launch_bounds__(1024) void k_sort1(const float* __restrict__ scores,
                                                uint64_t* __restrict__ keys,
                                                uint32_t* __restrict__ cnt,
                                                uint32_t* __restrict__ ovfc) {
    __shared__ uint64_t sk[2048];
    int b = blockIdx.x, t = threadIdx.x;
    int base = b * 2048;
    // zero the per-row packed-entry counters (must happen before k_mask).
    cnt[base + t] = 0;
    cnt[base + t + 1024] = 0;
    if (b == 0 && t == 0) *ovfc = 0;
    for (int e = 0; e < 2; ++e) {
        int li = t + e * 1024;
        int i = base + li;
        uint32_t sb = __float_as_uint(scores[i]);
        sb = (sb & 0x80000000u) ? ~sb : (sb | 0x80000000u);
        sk[li] = ((uint64_t)(~sb) << 32) | (uint32_t)i;
    }
    __syncthreads();
    for (int k = 2; k <= 2048; k <<= 1) {
        for (int j = k >> 1; j > 0; j >>= 1) {
            for (int e = 0; e < 2; ++e) {
                int li = t + e * 1024;
                int lixj = li ^ j;
                if (lixj > li) {
                    int gi = base + li;
                    bool up = ((gi & k) == 0);
                    uint64_t a = sk[li], c = sk[lixj];
                    if ((a > c) == up) { sk[li] = c; sk[lixj] = a; }
                }
            }
            __syncthreads();
        }
    }
    for (int e = 0; e < 2; ++e) { int li = t + e * 1024; keys[base + li] = sk[li]; }
}

// k=4096: cross pass j=2048 read from global (element-wise), then local j<=1024.
__global__ __launch_bounds__(1024) void k_sort2(const uint64_t* __restrict__ keys,
                                                uint64_t* __restrict__ keys2) {
    __shared__ uint64_t sk[2048];
    int b = blockIdx.x, t = threadIdx.x;
    int base = b * 2048;
    for (int e = 0; e < 2; ++e) {
        int li = t + e * 1024;
        int i = base + li;
        uint64_t a = keys[i], c = keys[i ^ 2048];
        bool up = ((i & 4096) == 0);
        bool lowpos = ((i & 2048) == 0);
        uint64_t mn = a < c ? a : c, mx = a < c ? c : a;
        sk[li] = (up == lowpos) ? mn : mx;
    }
    __syncthreads();
    for (int j = 1024; j > 0; j >>= 1) {
        for (int e = 0; e < 2; ++e) {
            int li = t + e * 1024;
            int lixj = li ^ j;
            if (lixj > li) {
                int gi = base + li;
                bool up = ((gi & 4096) == 0);
                uint64_t a = sk[li], c = sk[lixj];
                if ((a > c) == up) { sk[li] = c; sk[lixj] = a; }
            }
        }
        __syncthreads();
    }
    for (int e = 0; e < 2; ++e) { int li = t + e * 1024; keys2[base + li] = sk[li]; }
}

// k=8192 (up=true everywhere): cross passes j=4096,2048 from global, local
// j<=1024, then fused gather of boxes/scores into sorted order.
__global__ __launch_bounds__(1024) void k_sort3(const uint64_t* __restrict__ keys2,
                                                const float4* __restrict__ boxes,
                                                const float* __restrict__ scores,
                                                float4* __restrict__ bs,
                                                float* __restrict__ ss) {
    __shared__ uint64_t sk[2048];
    int b = blockIdx.x, t = threadIdx.x;
    int base = b * 2048;
    for (int e = 0; e < 2; ++e) {
        int li = t + e * 1024;
        int i = base + li;
        uint64_t a0 = keys2[i], a1 = keys2[i ^ 4096];
        bool low0 = ((i & 4096) == 0);
        uint64_t v = low0 ? (a0 < a1 ? a0 : a1) : (a0 < a1 ? a1 : a0);
        int q = i ^ 2048;
        uint64_t b0 = keys2[q], b1 = keys2[q ^ 4096];
        bool lowq = ((q & 4096) == 0);
        uint64_t vq = lowq ? (b0 < b1 ? b0 : b1) : (b0 < b1 ? b1 : b0);
        bool low2 = ((i & 2048) == 0);
        sk[li] = low2 ? (v < vq ? v : vq) : (v < vq ? vq : v);
    }
    __syncthreads();
    for (int j = 1024; j > 0; j >>= 1) {
        for (int e = 0; e < 2; ++e) {
            int li = t + e * 1024;
            int lixj = li ^ j;
            if (lixj > li) {
                uint64_t a = sk[li], c = sk[lixj];
                if (a > c) { sk[li] = c; sk[lixj] = a; }   // up = true
            }
        }
        __syncthreads();
    }
    for (int e = 0; e < 2; ++e) {
        int li = t + e * 1024;
        int gi = base + li;
        uint32_t idx = (uint32_t)sk[li];
        bs[gi] = boxes[idx];
        ss[gi] = scores[idx];
    }
}

// ---------------- Suppression bitmask -> sparse packed ----------------
// One wave per upper-triangle (R, word) tile; 8256 tiles = 2064 blocks x 4
// waves, perfectly balanced, zero barriers. Per row: diag word to diag[],
// nonzero off-diagonal words appended (atomicAdd cnt) to transposed
// pkT[e*N+row]; entries beyond CAP go to a tiny global overflow list.
__global__ __launch_bounds__(256) void k_mask(const float4* __restrict__ bs,
                                              ulonglong2* __restrict__ pkT,
                                              uint32_t* __restrict__ cnt,
                                              uint64_t* __restrict__ diag,
                                              ulonglong2* __restrict__ ovf,
                                              uint32_t* __restrict__ ovfc) {
    __shared__ float4 rb[4][64];
    __shared__ float  ra[4][64];
    int t = threadIdx.x;
    int lane = t & 63;
    int wv = t >> 6;
    int tile = blockIdx.x * 4 + wv;          // 0..8255

    // decode tile -> (R, word): off(R) = 128R - R(R-1)/2, word >= R
    int R = (int)((257.0 - sqrt(66049.0 - 8.0 * (double)tile)) * 0.5);
    while (128 * (R + 1) - ((R + 1) * R) / 2 <= tile) ++R;   // safety correction
    while (128 * R - (R * (R - 1)) / 2 > tile) --R;
    int word = R + tile - (128 * R - (R * (R - 1)) / 2);

    {   // stage this wave's 64 row boxes (wave-private LDS, no barrier needed)
        float4 b = bs[R * 64 + lane];
        rb[wv][lane] = b;
        ra[wv][lane] = ((b.z - b.x) + 1.0f) * ((b.w - b.y) + 1.0f);
    }
    int col = word * 64 + lane;
    float4 cb = bs[col];
    float ca = ((cb.z - cb.x) + 1.0f) * ((cb.w - cb.y) + 1.0f);

    for (int r = 0; r < 64; ++r) {
        int row = R * 64 + r;
        float4 rbv = rb[wv][r];
        float ix1 = fmaxf(rbv.x, cb.x);
        float iy1 = fmaxf(rbv.y, cb.y);
        float ix2 = fminf(rbv.z, cb.z);
        float iy2 = fminf(rbv.w, cb.w);
        float iw = fmaxf((ix2 - ix1) + 1.0f, 0.0f);
        float ih = fmaxf((iy2 - iy1) + 1.0f, 0.0f);
        float inter = iw * ih;
        float uni = (ra[wv][r] + ca) - inter;   // matches ref order
        float iou = inter / uni;                // IEEE div, matches numpy ref
        bool pred = (iou > 0.5f) && (col > row);
        uint64_t bal = __ballot(pred);
        if (lane == 0) {
            if (word == R) {
                diag[row] = bal;                 // intra-chunk word
            } else if (bal) {
                uint32_t pos = atomicAdd(&cnt[row], 1u);
                if (pos < CAP) {
                    ulonglong2 v;
                    v.x = bal; v.y = (unsigned long long)word;
                    pkT[(size_t)pos * N + row] = v;
                } else {
                    uint32_t op = atomicAdd(ovfc, 1u);
                    if (op < OVF_MAX) {
                        ulonglong2 v;
                        v.x = bal;
                        v.y = (unsigned long long)word |
                              ((unsigned long long)row << 32);
                        ovf[op] = v;
                    }
                }
            }
        }
    }
}

// ---------------- Sparse single-wave greedy scan ----------------
// 64 threads, zero barriers. Named scalar pipeline registers (SROA-proof) at
// depth 2, with sched_barrier(0) pinning the load-issue point so the compiler
// cannot sink the prefetch to its use (R9: VGPR=48 proved it sank them).
// Overflow list fully preloaded into registers (<=256 entries, 4/lane):
// per-chunk sweep is pure VALU, no exposed global loads.
__global__ __launch_bounds__(64, 1) void k_scan(const ulonglong2* __restrict__ pkT,
                                                const uint32_t* __restrict__ cnt,
                                                const uint64_t* __restrict__ diag,
                                                const ulonglong2* __restrict__ ovf,
                                                const uint32_t* __restrict__ ovfc,
                                                uint64_t* __restrict__ keepw) {
    __shared__ uint64_t sh_remv[128];
    const int lane = threadIdx.x;
    sh_remv[lane] = 0;
    sh_remv[64 + lane] = 0;
    const int novf = min((int)*ovfc, OVF_MAX);

    // preload overflow list into registers (disabled slots: y=~0 -> chunk -1)
    ulonglong2 o0, o1, o2, o3;
    o0.x = 0; o0.y = ~0ull; o1 = o0; o2 = o0; o3 = o0;
    if (lane < novf)       o0 = ovf[lane];
    if (lane + 64 < novf)  o1 = ovf[lane + 64];
    if (lane + 128 < novf) o2 = ovf[lane + 128];
    if (lane + 192 < novf) o3 = ovf[lane + 192];

    // pipeline registers: A = even chunks, B = odd chunks (depth 2)
    ulonglong2 A0,A1,A2,A3,A4,A5,A6,A7, B0,B1,B2,B3,B4,B5,B6,B7;
    uint64_t dA, dB; uint32_t cA, cB;
    dA = diag[lane];      cA = cnt[lane];
    dB = diag[64+lane];   cB = cnt[64+lane];
    A0 = pkT[(size_t)0*N+lane]; A1 = pkT[(size_t)1*N+lane];
    A2 = pkT[(size_t)2*N+lane]; A3 = pkT[(size_t)3*N+lane];
    A4 = pkT[(size_t)4*N+lane]; A5 = pkT[(size_t)5*N+lane];
    A6 = pkT[(size_t)6*N+lane]; A7 = pkT[(size_t)7*N+lane];
    {
        int nb = 64 + lane;
        B0 = pkT[(size_t)0*N+nb]; B1 = pkT[(size_t)1*N+nb];
        B2 = pkT[(size_t)2*N+nb]; B3 = pkT[(size_t)3*N+nb];
        B4 = pkT[(size_t)4*N+nb]; B5 = pkT[(size_t)5*N+nb];
        B6 = pkT[(size_t)6*N+nb]; B7 = pkT[(size_t)7*N+nb];
    }

#define OVAPP(OK)                                                              \
    {                                                                          \
        int er = (int)(OK .y >> 32);                                           \
        if ((er >> 6) == c_ && !((w_ >> (er & 63)) & 1ull))                    \
            atomicOr((unsigned long long*)&sh_remv[(int)(uint32_t)(OK .y)],    \
                     (unsigned long long)(OK .x));                             \
    }

// NOTE: "X##0 .x" (space before the dot) -- "0.x" would lex as one pp-number
// and break token pasting (R13 compile failure).
#define PROCESS(C_, X, DX, CX)                                                 \
    {                                                                          \
        const int c_ = (C_);                                                   \
        uint64_t d_cur = DX;                                                   \
        uint32_t c_cur = CX;                                                   \
        /* consume entries into locals, then refill X for chunk c_+2 */        \
        uint64_t v0 = X##0 .x; int w0 = (int)(X##0 .y);                        \
        uint64_t v1 = X##1 .x; int w1 = (int)(X##1 .y);                        \
        uint64_t v2 = X##2 .x; int w2 = (int)(X##2 .y);                        \
        uint64_t v3 = X##3 .x; int w3 = (int)(X##3 .y);                        \
        uint64_t v4 = X##4 .x; int w4 = (int)(X##4 .y);                        \
        uint64_t v5 = X##5 .x; int w5 = (int)(X##5 .y);                        \
        uint64_t v6 = X##6 .x; int w6 = (int)(X##6 .y);                        \
        uint64_t v7 = X##7 .x; int w7 = (int)(X##7 .y);                        \
        if (c_ + 2 < 128) {                                                    \
            int nb = (c_ + 2) * 64 + lane;                                     \
            X##0 = pkT[(size_t)0*N+nb]; X##1 = pkT[(size_t)1*N+nb];            \
            X##2 = pkT[(size_t)2*N+nb]; X##3 = pkT[(size_t)3*N+nb];            \
            X##4 = pkT[(size_t)4*N+nb]; X##5 = pkT[(size_t)5*N+nb];            \
            X##6 = pkT[(size_t)6*N+nb]; X##7 = pkT[(size_t)7*N+nb];            \
            DX = diag[nb];                                                     \
            CX = cnt[nb];                                                      \
        }                                                                      \
        __builtin_amdgcn_sched_barrier(0);   /* pin prefetch issue here */     \
        /* sparse scalar serial recurrence */                                  \
        uint64_t nzv = __ballot(d_cur != 0);                                   \
        uint32_t nlo = __builtin_amdgcn_readfirstlane((uint32_t)nzv);          \
        uint32_t nhi = __builtin_amdgcn_readfirstlane((uint32_t)(nzv >> 32));  \
        uint64_t nz = ((uint64_t)nhi << 32) | nlo;                             \
        uint32_t mlo = (uint32_t)d_cur, mhi = (uint32_t)(d_cur >> 32);         \
        asm volatile("s_waitcnt lgkmcnt(0)" ::: "memory");                     \
        uint64_t wvv = sh_remv[c_];                                            \
        uint32_t wlo = __builtin_amdgcn_readfirstlane((uint32_t)wvv);          \
        uint32_t whi = __builtin_amdgcn_readfirstlane((uint32_t)(wvv >> 32));  \
        uint64_t w_ = ((uint64_t)whi << 32) | wlo;                             \
        while (nz) {                                                           \
            int i = (int)__builtin_ctzll(nz);                                  \
            nz &= nz - 1;                                                      \
            if (!((w_ >> i) & 1ull)) {                                         \
                uint32_t lo = __builtin_amdgcn_readlane(mlo, i);               \
                uint32_t hi = __builtin_amdgcn_readlane(mhi, i);               \
                w_ |= ((uint64_t)hi << 32) | lo;                               \
            }                                                                  \
        }                                                                      \
        if (lane == 0) sh_remv[c_] = w_;                                       \
        if (!((w_ >> lane) & 1ull)) {  /* kept: scatter future words */        \
            if (0 < (int)c_cur) atomicOr((unsigned long long*)&sh_remv[w0], (unsigned long long)v0); \
            if (1 < (int)c_cur) atomicOr((unsigned long long*)&sh_remv[w1], (unsigned long long)v1); \
            if (2 < (int)c_cur) atomicOr((unsigned long long*)&sh_remv[w2], (unsigned long long)v2); \
            if (3 < (int)c_cur) atomicOr((unsigned long long*)&sh_remv[w3], (unsigned long long)v3); \
            if (4 < (int)c_cur) atomicOr((unsigned long long*)&sh_remv[w4], (unsigned long long)v4); \
            if (5 < (int)c_cur) atomicOr((unsigned long long*)&sh_remv[w5], (unsigned long long)v5); \
            if (6 < (int)c_cur) atomicOr((unsigned long long*)&sh_remv[w6], (unsigned long long)v6); \
            if (7 < (int)c_cur) atomicOr((unsigned long long*)&sh_remv[w7], (unsigned long long)v7); \
        }                                                                      \
        /* overflow completion from registers (no global loads) */             \
        OVAPP(o0) OVAPP(o1) OVAPP(o2) OVAPP(o3)                                \
        if (novf > 256) {  /* exact fallback beyond register capacity */       \
            uint64_t ovb = __ballot(c_cur > CAP);                              \
            if (ovb) {                                                         \
                for (int e = 256 + lane; e < novf; e += 64) {                  \
                    ulonglong2 en = ovf[e];                                    \
                    int erow = (int)(en.y >> 32);                              \
                    if ((erow >> 6) == c_ && !((w_ >> (erow & 63)) & 1ull))    \
                        atomicOr((unsigned long long*)&sh_remv[(int)(uint32_t)en.y],\
                                 (unsigned long long)en.x);                    \
                }                                                              \
            }                                                                  \
        }                                                                      \
    }

    for (int cc = 0; cc < 128; cc += 2) {
        PROCESS(cc,     A, dA, cA)
        PROCESS(cc + 1, B, dB, cB)
    }
#undef PROCESS
#undef OVAPP

    // single coalesced keep write-out
    asm volatile("s_waitcnt lgkmcnt(0)" ::: "memory");
    keepw[lane] = ~sh_remv[lane];
    keepw[64 + lane] = ~sh_remv[64 + lane];
}

// ---------------- Masked outputs ----------------
__global__ void k_out(const float4* __restrict__ bs, const float* __restrict__ ss,
                      const uint64_t* __restrict__ keepw, float* __restrict__ out) {
    int i = blockIdx.x * blockDim.x + threadIdx.x;
    uint64_t wv = keepw[i >> 6];
    float m = ((wv >> (i & 63)) & 1ull) ? 1.0f : 0.0f;
    float4 b = bs[i];
    float4 ob;
    ob.x = b.x * m; ob.y = b.y * m; ob.z = b.z * m; ob.w = b.w * m;
    ((float4*)out)[i] = ob;
    out[4 * N + i] = ss[i] * m;
    out[5 * N + i] = m;
}

extern "C" void kernel_launch(void* const* d_in, const int* in_sizes, int n_in,
                              void* d_out, int out_size, void* d_ws, size_t ws_size,
                              hipStream_t stream) {
    const float* boxes  = (const float*)d_in[0];   // 8192 x 4 f32
    const float* scores = (const float*)d_in[1];   // 8192 f32

    char* ws = (char*)d_ws;
    float4*     bs    = (float4*)(ws + 0);          // 131072 B
    float*      ss    = (float*)(ws + 131072);      //  32768 B
    uint64_t*   keepw = (uint64_t*)(ws + 163840);   //   1024 B
    uint32_t*   cnt   = (uint32_t*)(ws + 164864);   //  32768 B
    uint64_t*   diag  = (uint64_t*)(ws + 197632);   //  65536 B
    uint32_t*   ovfc  = (uint32_t*)(ws + 263168);   //      4 B (padded)
    ulonglong2* ovf   = (ulonglong2*)(ws + 263680); //  65536 B (4096 x 16)
    uint64_t*   keys  = (uint64_t*)(ws + 329216);   //  65536 B
    uint64_t*   keys2 = (uint64_t*)(ws + 394752);   //  65536 B
    ulonglong2* pkT   = (ulonglong2*)(ws + 524288); // 1048576 B (CAP x N x 16)

    k_sort1<<<4, 1024, 0, stream>>>(scores, keys, cnt, ovfc);
    k_sort2<<<4, 1024, 0, stream>>>(keys, keys2);
    k_sort3<<<4, 1024, 0, stream>>>(keys2, (const float4*)boxes, scores, bs, ss);
    k_mask <<<2064, 256, 0, stream>>>(bs, pkT, cnt, diag, ovf, ovfc);
    k_scan <<<1, 64, 0, stream>>>(pkT, cnt, diag, ovf, ovfc, keepw);
    k_out  <<<N / 256, 256, 0, stream>>>(bs, ss, keepw, (float*)d_out);
}

// Round 16
// 146.711 us; speedup vs baseline: 1.1474x; 1.0220x over previous
//
#include <hip/hip_runtime.h>
#include <stdint.h>
#include <math.h>

#define N 8192
#define CAP 8
#define OVF_MAX 4096

// ================= Sort stage (bitonic, exact argsort) =================
// key = (~monotone(score) << 32) | index; ascending sort == stable argsort
// of -scores. Network split: local k<=2048 (s1), k=4096 (s2), k=8192 (s3).

__global__ __launch_bounds__(1024) void k_sort1(const float* __restrict__ scores,
                                                uint64_t* __restrict__ keys,
                                                uint32_t* __restrict__ cnt,
                                                uint64_t* __restrict__ diag2,
                                                uint32_t* __restrict__ ovfc) {
    __shared__ uint64_t sk[2048];
    int b = blockIdx.x, t = threadIdx.x;
    int base = b * 2048;
    // zero per-row entry counters and the 2-word diag blocks (pre-k_mask).
    cnt[base + t] = 0;
    cnt[base + t + 1024] = 0;
    {
        int q = (b * 1024 + t) * 4;          // 16384 u64 total, 4 per thread
        diag2[q] = 0; diag2[q + 1] = 0; diag2[q + 2] = 0; diag2[q + 3] = 0;
    }
    if (b == 0 && t == 0) *ovfc = 0;
    for (int e = 0; e < 2; ++e) {
        int li = t + e * 1024;
        int i = base + li;
        uint32_t sb = __float_as_uint(scores[i]);
        sb = (sb & 0x80000000u) ? ~sb : (sb | 0x80000000u);
        sk[li] = ((uint64_t)(~sb) << 32) | (uint32_t)i;
    }
    __syncthreads();
    for (int k = 2; k <= 2048; k <<= 1) {
        for (int j = k >> 1; j > 0; j >>= 1) {
            for (int e = 0; e < 2; ++e) {
                int li = t + e * 1024;
                int lixj = li ^ j;
                if (lixj > li) {
                    int gi = base + li;
                    bool up = ((gi & k) == 0);
                    uint64_t a = sk[li], c = sk[lixj];
                    if ((a > c) == up) { sk[li] = c; sk[lixj] = a; }
                }
            }
            __syncthreads();
        }
    }
    for (int e = 0; e < 2; ++e) { int li = t + e * 1024; keys[base + li] = sk[li]; }
}

// k=4096: cross pass j=2048 read from global (element-wise), then local j<=1024.
__global__ __launch_bounds__(1024) void k_sort2(const uint64_t* __restrict__ keys,
                                                uint64_t* __restrict__ keys2) {
    __shared__ uint64_t sk[2048];
    int b = blockIdx.x, t = threadIdx.x;
    int base = b * 2048;
    for (int e = 0; e < 2; ++e) {
        int li = t + e * 1024;
        int i = base + li;
        uint64_t a = keys[i], c = keys[i ^ 2048];
        bool up = ((i & 4096) == 0);
        bool lowpos = ((i & 2048) == 0);
        uint64_t mn = a < c ? a : c, mx = a < c ? c : a;
        sk[li] = (up == lowpos) ? mn : mx;
    }
    __syncthreads();
    for (int j = 1024; j > 0; j >>= 1) {
        for (int e = 0; e < 2; ++e) {
            int li = t + e * 1024;
            int lixj = li ^ j;
            if (lixj > li) {
                int gi = base + li;
                bool up = ((gi & 4096) == 0);
                uint64_t a = sk[li], c = sk[lixj];
                if ((a > c) == up) { sk[li] = c; sk[lixj] = a; }
            }
        }
        __syncthreads();
    }
    for (int e = 0; e < 2; ++e) { int li = t + e * 1024; keys2[base + li] = sk[li]; }
}

// k=8192 (up=true everywhere): cross passes j=4096,2048 from global, local
// j<=1024, then fused gather of boxes/scores into sorted order.
__global__ __launch_bounds__(1024) void k_sort3(const uint64_t* __restrict__ keys2,
                                                const float4* __restrict__ boxes,
                                                const float* __restrict__ scores,
                                                float4* __restrict__ bs,
                                                float* __restrict__ ss) {
    __shared__ uint64_t sk[2048];
    int b = blockIdx.x, t = threadIdx.x;
    int base = b * 2048;
    for (int e = 0; e < 2; ++e) {
        int li = t + e * 1024;
        int i = base + li;
        uint64_t a0 = keys2[i], a1 = keys2[i ^ 4096];
        bool low0 = ((i & 4096) == 0);
        uint64_t v = low0 ? (a0 < a1 ? a0 : a1) : (a0 < a1 ? a1 : a0);
        int q = i ^ 2048;
        uint64_t b0 = keys2[q], b1 = keys2[q ^ 4096];
        bool lowq = ((q & 4096) == 0);
        uint64_t vq = lowq ? (b0 < b1 ? b0 : b1) : (b0 < b1 ? b1 : b0);
        bool low2 = ((i & 2048) == 0);
        sk[li] = low2 ? (v < vq ? v : vq) : (v < vq ? vq : v);
    }
    __syncthreads();
    for (int j = 1024; j > 0; j >>= 1) {
        for (int e = 0; e < 2; ++e) {
            int li = t + e * 1024;
            int lixj = li ^ j;
            if (lixj > li) {
                uint64_t a = sk[li], c = sk[lixj];
                if (a > c) { sk[li] = c; sk[lixj] = a; }   // up = true
            }
        }
        __syncthreads();
    }
    for (int e = 0; e < 2; ++e) {
        int li = t + e * 1024;
        int gi = base + li;
        uint32_t idx = (uint32_t)sk[li];
        bs[gi] = boxes[idx];
        ss[gi] = scores[idx];
    }
}

// ---------------- Suppression bitmask -> sparse packed ----------------
// One wave per upper-triangle (R, word) tile; 8256 tiles = 2064 blocks x 4
// waves. Intra-128-row-block words (word>>1 == R>>1) go to diag2[row*2+slot];
// off-block nonzero words appended (atomicAdd cnt) to transposed pkT[e*N+row];
// entries beyond CAP go to the global overflow list.
__global__ __launch_bounds__(256) void k_mask(const float4* __restrict__ bs,
                                              ulonglong2* __restrict__ pkT,
                                              uint32_t* __restrict__ cnt,
                                              uint64_t* __restrict__ diag2,
                                              ulonglong2* __restrict__ ovf,
                                              uint32_t* __restrict__ ovfc) {
    __shared__ float4 rb[4][64];
    __shared__ float  ra[4][64];
    int t = threadIdx.x;
    int lane = t & 63;
    int wv = t >> 6;
    int tile = blockIdx.x * 4 + wv;          // 0..8255

    // decode tile -> (R, word): off(R) = 128R - R(R-1)/2, word >= R
    int R = (int)((257.0 - sqrt(66049.0 - 8.0 * (double)tile)) * 0.5);
    while (128 * (R + 1) - ((R + 1) * R) / 2 <= tile) ++R;   // safety correction
    while (128 * R - (R * (R - 1)) / 2 > tile) --R;
    int word = R + tile - (128 * R - (R * (R - 1)) / 2);

    {   // stage this wave's 64 row boxes (wave-private LDS, no barrier needed)
        float4 b = bs[R * 64 + lane];
        rb[wv][lane] = b;
        ra[wv][lane] = ((b.z - b.x) + 1.0f) * ((b.w - b.y) + 1.0f);
    }
    int col = word * 64 + lane;
    float4 cb = bs[col];
    float ca = ((cb.z - cb.x) + 1.0f) * ((cb.w - cb.y) + 1.0f);

    for (int r = 0; r < 64; ++r) {
        int row = R * 64 + r;
        float4 rbv = rb[wv][r];
        float ix1 = fmaxf(rbv.x, cb.x);
        float iy1 = fmaxf(rbv.y, cb.y);
        float ix2 = fminf(rbv.z, cb.z);
        float iy2 = fminf(rbv.w, cb.w);
        float iw = fmaxf((ix2 - ix1) + 1.0f, 0.0f);
        float ih = fmaxf((iy2 - iy1) + 1.0f, 0.0f);
        float inter = iw * ih;
        float uni = (ra[wv][r] + ca) - inter;   // matches ref order
        float iou = inter / uni;                // IEEE div, matches numpy ref
        bool pred = (iou > 0.5f) && (col > row);
        uint64_t bal = __ballot(pred);
        if (lane == 0) {
            if ((word >> 1) == (R >> 1)) {
                diag2[row * 2 + (word & 1)] = bal;   // intra-block word
            } else if (bal) {
                uint32_t pos = atomicAdd(&cnt[row], 1u);
                if (pos < CAP) {
                    ulonglong2 v;
                    v.x = bal; v.y = (unsigned long long)word;
                    pkT[(size_t)pos * N + row] = v;
                } else {
                    uint32_t op = atomicAdd(ovfc, 1u);
                    if (op < OVF_MAX) {
                        ulonglong2 v;
                        v.x = bal;
                        v.y = (unsigned long long)word |
                              ((unsigned long long)row << 32);
                        ovf[op] = v;
                    }
                }
            }
        }
    }
}

// ---------------- Sparse single-wave greedy scan (128-row blocks) ----------
// 64 threads, zero barriers, 64 rounds. All readlane/readfirstlane results
// pass through explicit uint32_t locals: the inlined form sign-extended the
// int-returning builtin into uint64_t ORs (R15 correctness failure).
__global__ __launch_bounds__(64, 1) void k_scan(const ulonglong2* __restrict__ pkT,
                                                const uint32_t* __restrict__ cnt,
                                                const uint64_t* __restrict__ diag2,
                                                const ulonglong2* __restrict__ ovf,
                                                const uint32_t* __restrict__ ovfc,
                                                uint64_t* __restrict__ keepw) {
    __shared__ uint64_t sh_remv[128];
    const int lane = threadIdx.x;
    sh_remv[lane] = 0;
    sh_remv[64 + lane] = 0;
    const int novf = min((int)*ovfc, OVF_MAX);

    // preload overflow list into registers (disabled slots: y=~0 -> block -1)
    ulonglong2 o0, o1, o2, o3;
    o0.x = 0; o0.y = ~0ull; o1 = o0; o2 = o0; o3 = o0;
    if (lane < novf)       o0 = ovf[lane];
    if (lane + 64 < novf)  o1 = ovf[lane + 64];
    if (lane + 128 < novf) o2 = ovf[lane + 128];
    if (lane + 192 < novf) o3 = ovf[lane + 192];

    // diag/cnt pipeline: A = even blocks, B = odd blocks (depth 2)
    uint64_t Ad0, Ad1, Ae1, Bd0, Bd1, Be1;
    uint32_t Acl, Acu, Bcl, Bcu;
    {
        int rl = lane, ru = 64 + lane;          // block 0
        Ad0 = diag2[rl * 2]; Ad1 = diag2[rl * 2 + 1]; Ae1 = diag2[ru * 2 + 1];
        Acl = cnt[rl]; Acu = cnt[ru];
        rl = 128 + lane; ru = 192 + lane;       // block 1
        Bd0 = diag2[rl * 2]; Bd1 = diag2[rl * 2 + 1]; Be1 = diag2[ru * 2 + 1];
        Bcl = cnt[rl]; Bcu = cnt[ru];
    }

#define RFL(x) __builtin_amdgcn_readfirstlane(x)
#define RL(x, i) __builtin_amdgcn_readlane(x, i)

#define PROCESS(B_, D0, D1, E1, CL, CU)                                        \
    {                                                                          \
        const int b_ = (B_);                                                   \
        uint64_t d0 = D0, d1 = D1, e1 = E1;                                    \
        uint32_t cl = CL, cu = CU;                                             \
        if (b_ + 2 < 64) {   /* refill diag/cnt pipe for block b_+2 */         \
            int rl = (b_ + 2) * 128 + lane, ru = rl + 64;                      \
            D0 = diag2[rl * 2]; D1 = diag2[rl * 2 + 1]; E1 = diag2[ru * 2 + 1];\
            CL = cnt[rl]; CU = cnt[ru];                                        \
        }                                                                      \
        /* issue this block's entry loads now; latency hides under recurrence */\
        int rlo = b_ * 128 + lane, rhi = rlo + 64;                             \
        ulonglong2 L0 = pkT[(size_t)0*N+rlo], L1 = pkT[(size_t)1*N+rlo];       \
        ulonglong2 L2 = pkT[(size_t)2*N+rlo], L3 = pkT[(size_t)3*N+rlo];       \
        ulonglong2 L4 = pkT[(size_t)4*N+rlo], L5 = pkT[(size_t)5*N+rlo];       \
        ulonglong2 L6 = pkT[(size_t)6*N+rlo], L7 = pkT[(size_t)7*N+rlo];       \
        ulonglong2 U0 = pkT[(size_t)0*N+rhi], U1 = pkT[(size_t)1*N+rhi];       \
        ulonglong2 U2 = pkT[(size_t)2*N+rhi], U3 = pkT[(size_t)3*N+rhi];       \
        ulonglong2 U4 = pkT[(size_t)4*N+rhi], U5 = pkT[(size_t)5*N+rhi];       \
        ulonglong2 U6 = pkT[(size_t)6*N+rhi], U7 = pkT[(size_t)7*N+rhi];       \
        __builtin_amdgcn_sched_barrier(0);   /* pin load issue above */        \
        /* ballots over the 2 row-phases (explicit u32 locals: no sext) */     \
        uint64_t bl64 = __ballot((d0 | d1) != 0);                              \
        uint64_t bu64 = __ballot(e1 != 0);                                     \
        uint32_t zll = RFL((uint32_t)bl64);                                    \
        uint32_t zlh = RFL((uint32_t)(bl64 >> 32));                            \
        uint32_t zul = RFL((uint32_t)bu64);                                    \
        uint32_t zuh = RFL((uint32_t)(bu64 >> 32));                            \
        uint64_t nzl = ((uint64_t)zlh << 32) | zll;                            \
        uint64_t nzu = ((uint64_t)zuh << 32) | zul;                            \
        uint32_t d0l = (uint32_t)d0, d0h = (uint32_t)(d0 >> 32);               \
        uint32_t d1l = (uint32_t)d1, d1h = (uint32_t)(d1 >> 32);               \
        uint32_t e1l = (uint32_t)e1, e1h = (uint32_t)(e1 >> 32);               \
        asm volatile("s_waitcnt lgkmcnt(0)" ::: "memory");                     \
        uint64_t w0v = sh_remv[2 * b_], w1v = sh_remv[2 * b_ + 1];             \
        uint32_t s0l = RFL((uint32_t)w0v), s0h = RFL((uint32_t)(w0v >> 32));   \
        uint32_t s1l = RFL((uint32_t)w1v), s1h = RFL((uint32_t)(w1v >> 32));   \
        uint64_t s0 = ((uint64_t)s0h << 32) | s0l;                             \
        uint64_t s1 = ((uint64_t)s1h << 32) | s1l;                             \
        while (nzl) {   /* phase 1: lower 64 rows in index order */            \
            int i = (int)__builtin_ctzll(nzl);                                 \
            nzl &= nzl - 1;                                                    \
            if (!((s0 >> i) & 1ull)) {                                         \
                uint32_t p0 = RL(d0l, i), p1 = RL(d0h, i);                     \
                uint32_t q0 = RL(d1l, i), q1 = RL(d1h, i);                     \
                s0 |= ((uint64_t)p1 << 32) | p0;                               \
                s1 |= ((uint64_t)q1 << 32) | q0;                               \
            }                                                                  \
        }                                                                      \
        while (nzu) {   /* phase 2: upper 64 rows in index order */            \
            int i = (int)__builtin_ctzll(nzu);                                 \
            nzu &= nzu - 1;                                                    \
            if (!((s1 >> i) & 1ull)) {                                         \
                uint32_t p0 = RL(e1l, i), p1 = RL(e1h, i);                     \
                s1 |= ((uint64_t)p1 << 32) | p0;                               \
            }                                                                  \
        }                                                                      \
        if (lane == 0) { sh_remv[2 * b_] = s0; sh_remv[2 * b_ + 1] = s1; }     \
        if (!((s0 >> lane) & 1ull)) {   /* lower row kept: scatter */          \
            if (0 < (int)cl) atomicOr((unsigned long long*)&sh_remv[(int)(L0.y)], (unsigned long long)(L0.x)); \
            if (1 < (int)cl) atomicOr((unsigned long long*)&sh_remv[(int)(L1.y)], (unsigned long long)(L1.x)); \
            if (2 < (int)cl) atomicOr((unsigned long long*)&sh_remv[(int)(L2.y)], (unsigned long long)(L2.x)); \
            if (3 < (int)cl) atomicOr((unsigned long long*)&sh_remv[(int)(L3.y)], (unsigned long long)(L3.x)); \
            if (4 < (int)cl) atomicOr((unsigned long long*)&sh_remv[(int)(L4.y)], (unsigned long long)(L4.x)); \
            if (5 < (int)cl) atomicOr((unsigned long long*)&sh_remv[(int)(L5.y)], (unsigned long long)(L5.x)); \
            if (6 < (int)cl) atomicOr((unsigned long long*)&sh_remv[(int)(L6.y)], (unsigned long long)(L6.x)); \
            if (7 < (int)cl) atomicOr((unsigned long long*)&sh_remv[(int)(L7.y)], (unsigned long long)(L7.x)); \
        }                                                                      \
        if (!((s1 >> lane) & 1ull)) {   /* upper row kept: scatter */          \
            if (0 < (int)cu) atomicOr((unsigned long long*)&sh_remv[(int)(U0.y)], (unsigned long long)(U0.x)); \
            if (1 < (int)cu) atomicOr((unsigned long long*)&sh_remv[(int)(U1.y)], (unsigned long long)(U1.x)); \
            if (2 < (int)cu) atomicOr((unsigned long long*)&sh_remv[(int)(U2.y)], (unsigned long long)(U2.x)); \
            if (3 < (int)cu) atomicOr((unsigned long long*)&sh_remv[(int)(U3.y)], (unsigned long long)(U3.x)); \
            if (4 < (int)cu) atomicOr((unsigned long long*)&sh_remv[(int)(U4.y)], (unsigned long long)(U4.x)); \
            if (5 < (int)cu) atomicOr((unsigned long long*)&sh_remv[(int)(U5.y)], (unsigned long long)(U5.x)); \
            if (6 < (int)cu) atomicOr((unsigned long long*)&sh_remv[(int)(U6.y)], (unsigned long long)(U6.x)); \
            if (7 < (int)cu) atomicOr((unsigned long long*)&sh_remv[(int)(U7.y)], (unsigned long long)(U7.x)); \
        }                                                                      \
        /* overflow completion from registers */                               \
        {                                                                      \
            int er = (int)(o0.y >> 32);                                        \
            if ((er >> 7) == b_) {                                             \
                uint64_t sb = (er & 64) ? s1 : s0;                             \
                if (!((sb >> (er & 63)) & 1ull))                               \
                    atomicOr((unsigned long long*)&sh_remv[(int)(uint32_t)o0.y], (unsigned long long)o0.x); \
            }                                                                  \
            er = (int)(o1.y >> 32);                                            \
            if ((er >> 7) == b_) {                                             \
                uint64_t sb = (er & 64) ? s1 : s0;                             \
                if (!((sb >> (er & 63)) & 1ull))                               \
                    atomicOr((unsigned long long*)&sh_remv[(int)(uint32_t)o1.y], (unsigned long long)o1.x); \
            }                                                                  \
            er = (int)(o2.y >> 32);                                            \
            if ((er >> 7) == b_) {                                             \
                uint64_t sb = (er & 64) ? s1 : s0;                             \
                if (!((sb >> (er & 63)) & 1ull))                               \
                    atomicOr((unsigned long long*)&sh_remv[(int)(uint32_t)o2.y], (unsigned long long)o2.x); \
            }                                                                  \
            er = (int)(o3.y >> 32);                                            \
            if ((er >> 7) == b_) {                                             \
                uint64_t sb = (er & 64) ? s1 : s0;                             \
                if (!((sb >> (er & 63)) & 1ull))                               \
                    atomicOr((unsigned long long*)&sh_remv[(int)(uint32_t)o3.y], (unsigned long long)o3.x); \
            }                                                                  \
        }                                                                      \
        if (novf > 256) {   /* exact fallback beyond register capacity */      \
            uint64_t ovb = __ballot(cl > CAP || cu > CAP);                     \
            if (ovb) {                                                         \
                for (int e = 256 + lane; e < novf; e += 64) {                  \
                    ulonglong2 en = ovf[e];                                    \
                    int erow = (int)(en.y >> 32);                              \
                    if ((erow >> 7) == b_) {                                   \
                        uint64_t sb = (erow & 64) ? s1 : s0;                   \
                        if (!((sb >> (erow & 63)) & 1ull))                     \
                            atomicOr((unsigned long long*)&sh_remv[(int)(uint32_t)en.y], \
                                     (unsigned long long)en.x);                \
                    }                                                          \
                }                                                              \
            }                                                                  \
        }                                                                      \
    }

    for (int bb = 0; bb < 64; bb += 2) {
        PROCESS(bb,     Ad0, Ad1, Ae1, Acl, Acu)
        PROCESS(bb + 1, Bd0, Bd1, Be1, Bcl, Bcu)
    }
#undef PROCESS
#undef RFL
#undef RL

    // single coalesced keep write-out
    asm volatile("s_waitcnt lgkmcnt(0)" ::: "memory");
    keepw[lane] = ~sh_remv[lane];
    keepw[64 + lane] = ~sh_remv[64 + lane];
}

// ---------------- Masked outputs ----------------
__global__ void k_out(const float4* __restrict__ bs, const float* __restrict__ ss,
                      const uint64_t* __restrict__ keepw, float* __restrict__ out) {
    int i = blockIdx.x * blockDim.x + threadIdx.x;
    uint64_t wv = keepw[i >> 6];
    float m = ((wv >> (i & 63)) & 1ull) ? 1.0f : 0.0f;
    float4 b = bs[i];
    float4 ob;
    ob.x = b.x * m; ob.y = b.y * m; ob.z = b.z * m; ob.w = b.w * m;
    ((float4*)out)[i] = ob;
    out[4 * N + i] = ss[i] * m;
    out[5 * N + i] = m;
}

extern "C" void kernel_launch(void* const* d_in, const int* in_sizes, int n_in,
                              void* d_out, int out_size, void* d_ws, size_t ws_size,
                              hipStream_t stream) {
    const float* boxes  = (const float*)d_in[0];   // 8192 x 4 f32
    const float* scores = (const float*)d_in[1];   // 8192 f32

    char* ws = (char*)d_ws;
    float4*     bs    = (float4*)(ws + 0);          // 131072 B
    float*      ss    = (float*)(ws + 131072);      //  32768 B
    uint64_t*   keepw = (uint64_t*)(ws + 163840);   //   1024 B
    uint32_t*   cnt   = (uint32_t*)(ws + 164864);   //  32768 B
    uint32_t*   ovfc  = (uint32_t*)(ws + 197632);   //    512 B (padded)
    ulonglong2* ovf   = (ulonglong2*)(ws + 198144); //  65536 B (4096 x 16)
    uint64_t*   diag2 = (uint64_t*)(ws + 263680);   // 131072 B (8192 x 2 u64)
    uint64_t*   keys  = (uint64_t*)(ws + 458752);   //  65536 B
    uint64_t*   keys2 = (uint64_t*)(ws + 524288);   //  65536 B
    ulonglong2* pkT   = (ulonglong2*)(ws + 1048576);// 1048576 B (CAP x N x 16)

    k_sort1<<<4, 1024, 0, stream>>>(scores, keys, cnt, diag2, ovfc);
    k_sort2<<<4, 1024, 0, stream>>>(keys, keys2);
    k_sort3<<<4, 1024, 0, stream>>>(keys2, (const float4*)boxes, scores, bs, ss);
    k_mask <<<2064, 256, 0, stream>>>(bs, pkT, cnt, diag2, ovf, ovfc);
    k_scan <<<1, 64, 0, stream>>>(pkT, cnt, diag2, ovf, ovfc, keepw);
    k_out  <<<N / 256, 256, 0, stream>>>(bs, ss, keepw, (float*)d_out);
}